// Round 11
// baseline (312.020 us; speedup 1.0000x reference)
//
#include <hip/hip_runtime.h>

typedef unsigned short u16;
typedef unsigned int u32;
typedef unsigned long long u64;
typedef __attribute__((ext_vector_type(8))) short short8;
typedef __attribute__((ext_vector_type(4))) float f32x4;

#define T_ 4096
#define QSCALE 0.18033688f   // (1/8) * log2(e): folded into Q at proj time
#define CH 4                 // key-tiles per chunk (r9 best config)
#define SBAT 576             // CH=4 slot count per bat (pnum/pden layout)
#define SGRID 288            // attn grid: 2 waves per chunk (2 q32 per wave)
#define PSTRIDE 36           // P strip row stride in u16 (72 B: 8B-aligned, bank-uniform)
#define ATTN_REPS 5          // CALIBRATION: in-kernel repeat to lift attn above the
                             // 44us poison-fills so rocprof top-5 shows its counters.
                             // Idempotent: all outputs fully overwritten each rep.

#if __has_builtin(__builtin_amdgcn_exp2f)
#define EXP2F(x) __builtin_amdgcn_exp2f(x)
#else
#define EXP2F(x) exp2f(x)
#endif

__device__ __forceinline__ u16 f2bf(float f) {
    unsigned u = __float_as_uint(f);
    u += 0x7FFFu + ((u >> 16) & 1u);   // RNE to bf16
    return (u16)(u >> 16);
}

// ---------------------------------------------------------------------------
// Kernel 0: W -> WTf in MFMA-B-fragment-contiguous order.
// ---------------------------------------------------------------------------
__global__ __launch_bounds__(256) void wtrans_kernel(
    const float* __restrict__ Wq, const float* __restrict__ Wk,
    const float* __restrict__ Wv, u16* __restrict__ WTf)
{
    const int tid  = blockIdx.x * 256 + threadIdx.x;   // 48*256 = 12288
    const int frag = tid >> 6;                          // 0..191
    const int lane = tid & 63;
    const int ng   = frag >> 4;
    const int kc   = frag & 15;
    const int m    = ng >> 2;
    const float* W = (m == 0) ? Wq : (m == 1) ? Wk : Wv;
    const int h  = (ng & 3) * 16 + (lane & 15);
    const int c0 = kc * 32 + (lane >> 4) * 8;
    short8 v;
    #pragma unroll
    for (int j = 0; j < 8; ++j)
        v[j] = (short)f2bf(W[(c0 + j) * 64 + h]);
    *(short8*)(WTf + (size_t)frag * 512 + lane * 8) = v;
}

// ---------------------------------------------------------------------------
// Kernel 1: projection. (Unchanged.)
// ---------------------------------------------------------------------------
__global__ __launch_bounds__(256) void proj_kernel(
    const float* __restrict__ x, const u16* __restrict__ WTf,
    u16* __restrict__ Qf, u16* __restrict__ Kf, u16* __restrict__ Vf)
{
    __shared__ u16 xs[16 * 520];
    __shared__ u16 img[3072];   // Q @0, K @1024, V @2048 (u16 units)
    const int t    = threadIdx.x;
    const int lane = t & 63;
    const int w    = t >> 6;
    const int l16  = lane & 15;
    const int quad = lane >> 4;
    const int rowbase = blockIdx.x * 16;
    const int bat  = rowbase >> 12;
    const int tloc = rowbase & 4095;

    #pragma unroll
    for (int it = 0; it < 8; ++it) {
        int f   = t + it * 256;                 // float4 index, coalesced
        int row = f >> 7;
        int c4  = (f & 127) * 4;
        f32x4 a = *(const f32x4*)(x + (size_t)(rowbase + row) * 512 + c4);
        unsigned lo = (unsigned)f2bf(a[0]) | ((unsigned)f2bf(a[1]) << 16);
        unsigned hi = (unsigned)f2bf(a[2]) | ((unsigned)f2bf(a[3]) << 16);
        *(uint2*)(xs + row * 520 + c4) = make_uint2(lo, hi);
    }
    __syncthreads();

    f32x4 acc[3];
    #pragma unroll
    for (int nt = 0; nt < 3; ++nt) acc[nt] = (f32x4){0.f, 0.f, 0.f, 0.f};

    const u16* ab = xs + l16 * 520 + quad * 8;
    const u16* wb = WTf + (size_t)(w * 3 * 16) * 512 + lane * 8;

    #pragma unroll 4
    for (int kc = 0; kc < 16; ++kc) {
        short8 af = *(const short8*)(ab + kc * 32);
        #pragma unroll
        for (int nt = 0; nt < 3; ++nt) {
            short8 bf = *(const short8*)(wb + (size_t)(nt * 16 + kc) * 512);
            acc[nt] = __builtin_amdgcn_mfma_f32_16x16x32_bf16(af, bf, acc[nt], 0, 0, 0);
        }
    }

    // ---- epilogue: scatter into LDS image ----
    #pragma unroll
    for (int nt = 0; nt < 3; ++nt) {
        int ng = w * 3 + nt;
        if (ng < 8) {
            int ng4  = ng & 3;
            float sc = (ng < 4) ? QSCALE : 1.0f;
            u16* ib  = img + ((ng < 4) ? 0 : 1024) + (ng4 >> 1) * 512
                          + ((ng4 & 1) * 2 + (l16 >> 3)) * 128 + (l16 & 7);
            #pragma unroll
            for (int i = 0; i < 4; ++i)
                ib[(quad * 4 + i) * 8] = f2bf(acc[nt][i] * sc);
        } else {
            int nt2  = ng - 8;
            unsigned lo = (unsigned)f2bf(acc[nt][0]) | ((unsigned)f2bf(acc[nt][1]) << 16);
            unsigned hi = (unsigned)f2bf(acc[nt][2]) | ((unsigned)f2bf(acc[nt][3]) << 16);
            *(uint2*)(img + 2048 + nt2 * 256 + (quad >> 1) * 128 + l16 * 8
                          + (quad & 1) * 4) = make_uint2(lo, hi);
        }
    }
    __syncthreads();

    // ---- coalesced copy-out ----
    const int tb   = tloc >> 4;
    const int kt   = tloc >> 7;
    const int ks   = (tloc >> 5) & 3;
    const int half = (tloc >> 4) & 1;
    uint2 vq = *(uint2*)(img + t * 4);
    uint2 vk = *(uint2*)(img + 1024 + t * 4);
    uint2 vv = *(uint2*)(img + 2048 + t * 4);
    *(uint2*)(Qf + (size_t)(bat * 256 + tb) * 1024 + t * 4) = vq;
    *(uint2*)(Kf + (size_t)(bat * 256 + tb) * 1024 + t * 4) = vk;
    const int nt2c = t >> 6;
    *(uint2*)(Vf + (size_t)((bat * 32 + kt) * 4 + ks) * 2048
                 + nt2c * 512 + half * 256 + (t & 63) * 4) = vv;
}

// ---------------------------------------------------------------------------
// Kernel 2: attention — r9 best config (CH=4, gg=4, 1-deep pipeline),
// wrapped in an ATTN_REPS in-kernel repeat for counter visibility.
// ---------------------------------------------------------------------------
__global__ __launch_bounds__(256, 2) void attn_kernel(
    const u16* __restrict__ Qf, const u16* __restrict__ Kf,
    const u16* __restrict__ Vf, u32* __restrict__ pnum,
    float* __restrict__ pden, float* __restrict__ out)
{
    __shared__ u16 Ps[4][2][4][16 * PSTRIDE];   // [wave][par][gg][...], 36.9 KB

    const int w    = threadIdx.x >> 6;
    const int lane = threadIdx.x & 63;
    const int l16  = lane & 15;
    const int qd   = lane >> 4;
    const int xcd  = blockIdx.x & 7;
    const int bat  = xcd >> 1;
    const int tw   = ((blockIdx.x >> 3) * 2 + (xcd & 1)) * 4 + w;  // 0..287

    int A = 31, pre = 0, cc = 1;
    for (;;) {                               // big-A first; pre counts 2 tasks/chunk
        cc = (A + CH) / CH;
        int cnt2 = 2 * cc;
        if (tw < pre + cnt2) break;
        pre += cnt2; --A;
    }
    const int r    = tw - pre;
    const int c    = r >> 1;                 // my chunk (shared by 2 waves)
    const int bp   = r & 1;                  // q32-pair index: q32 = 4A+2bp+{0,1}
    const int nkt  = A + 1;
    const int q32a = 4 * A + 2 * bp;
    const int kt0  = c * CH;
    const int kt1  = min(kt0 + CH, nkt);
    const int slot0 = bat * SBAT + 2 * pre + 2 * bp + 4 * c;   // j=0; j=1 at +1

    short8 aq[4][2];                         // gg = j*2 + g
    #pragma unroll
    for (int gg = 0; gg < 4; ++gg)
        #pragma unroll
        for (int f = 0; f < 2; ++f)
            aq[gg][f] = *(const short8*)(Qf
                + ((size_t)((bat * 256 + (q32a + (gg >> 1)) * 2 + (gg & 1)) * 2 + f)) * 512 + lane * 8);

    // constant-ones A-fragment for the den MFMA (bf16 1.0 = 0x3F80)
    short8 ones;
    #pragma unroll
    for (int j = 0; j < 8; ++j) ones[j] = (short)0x3F80;

    u16* Psw = &Ps[w][0][0][0];    // par stride 2304 u16, gg stride 576

    #pragma unroll 1
    for (int rep = 0; rep < ATTN_REPS; ++rep) {
        f32x4 acc[4][4];
        f32x4 accden[4];
        #pragma unroll
        for (int gg = 0; gg < 4; ++gg) {
            accden[gg] = (f32x4){0.f, 0.f, 0.f, 0.f};
            #pragma unroll
            for (int n = 0; n < 4; ++n) acc[gg][n] = (f32x4){0.f, 0.f, 0.f, 0.f};
        }

        int par = 0;
        short8 ap_prev[4];
        short8 av_prev[4];

        auto step = [&](int kt, int ks, bool first) __attribute__((always_inline)) {
            const u16* kfb = Kf + ((size_t)(bat * 256 + kt * 8) * 2) * 512 + lane * 8;
            const u16* vfb = Vf + ((size_t)((bat * 32 + kt) * 16)) * 512 + lane * 8;
            // ---- (a) K loads + QK MFMAs -> st regs (each K frag feeds 4 gg) ----
            f32x4 st[2][4];
            #pragma unroll
            for (int b = 0; b < 2; ++b) {
                short8 k0 = *(const short8*)(kfb + (size_t)(2 * ks + b) * 1024);
                short8 k1 = *(const short8*)(kfb + (size_t)(2 * ks + b) * 1024 + 512);
                #pragma unroll
                for (int gg = 0; gg < 4; ++gg) {
                    f32x4 s = (f32x4){0.f, 0.f, 0.f, 0.f};
                    s = __builtin_amdgcn_mfma_f32_16x16x32_bf16(k0, aq[gg][0], s, 0, 0, 0);
                    s = __builtin_amdgcn_mfma_f32_16x16x32_bf16(k1, aq[gg][1], s, 0, 0, 0);
                    st[b][gg] = s;
                }
            }
            // ---- (b) den + PV MFMAs for the PREVIOUS step ----
            if (!first) {
                #pragma unroll
                for (int gg = 0; gg < 4; ++gg)
                    accden[gg] = __builtin_amdgcn_mfma_f32_16x16x32_bf16(ones, ap_prev[gg], accden[gg], 0, 0, 0);
                #pragma unroll
                for (int nt2 = 0; nt2 < 4; ++nt2)
                    #pragma unroll
                    for (int gg = 0; gg < 4; ++gg)
                        acc[gg][nt2] = __builtin_amdgcn_mfma_f32_16x16x32_bf16(av_prev[nt2], ap_prev[gg], acc[gg][nt2], 0, 0, 0);
            }
            // ---- (c) exp -> pack -> strip write (parity par) ----
            u16* sw = Psw + par * 2304;
            #pragma unroll
            for (int b = 0; b < 2; ++b) {
                #pragma unroll
                for (int gg = 0; gg < 4; ++gg) {
                    f32x4 s = st[b][gg];
                    float p0 = EXP2F(s[0]);
                    float p1 = EXP2F(s[1]);
                    float p2 = EXP2F(s[2]);
                    float p3 = EXP2F(s[3]);
                    u32 q01 = __builtin_amdgcn_perm(__float_as_uint(p1), __float_as_uint(p0), 0x07060302u);
                    u32 q23 = __builtin_amdgcn_perm(__float_as_uint(p3), __float_as_uint(p2), 0x07060302u);
                    u64 pv = (u64)q01 | ((u64)q23 << 32);
                    *(u64*)(sw + gg * 576 + l16 * PSTRIDE + b * 16 + qd * 4) = pv;
                }
            }
            // ---- (d) issue next-step consumables: V loads + strip reads ----
            #pragma unroll
            for (int nt2 = 0; nt2 < 4; ++nt2)
                av_prev[nt2] = *(const short8*)(vfb + (size_t)(ks * 4 + nt2) * 512);
            #pragma unroll
            for (int gg = 0; gg < 4; ++gg)
                ap_prev[gg] = *(const short8*)(sw + gg * 576 + l16 * PSTRIDE + qd * 8);
            par ^= 1;
        };

        auto body = [&](int kt, bool firstb) __attribute__((always_inline)) {
            step(kt, 0, firstb);
            step(kt, 1, false);
            step(kt, 2, false);
            step(kt, 3, false);
        };

        // straight-line the <=4 key-tile iterations (no dynamic loop)
        body(kt0, true);
        if (kt0 + 1 < kt1) body(kt0 + 1, false);
        if (kt0 + 2 < kt1) body(kt0 + 2, false);
        if (kt0 + 3 < kt1) body(kt0 + 3, false);

        // ---- drain: den + PV for the final step ----
        #pragma unroll
        for (int gg = 0; gg < 4; ++gg)
            accden[gg] = __builtin_amdgcn_mfma_f32_16x16x32_bf16(ones, ap_prev[gg], accden[gg], 0, 0, 0);
        #pragma unroll
        for (int nt2 = 0; nt2 < 4; ++nt2)
            #pragma unroll
            for (int gg = 0; gg < 4; ++gg)
                acc[gg][nt2] = __builtin_amdgcn_mfma_f32_16x16x32_bf16(av_prev[nt2], ap_prev[gg], acc[gg][nt2], 0, 0, 0);

        // den is replicated across rows by the ones-MFMA: lane-local, no reduce
        float den[4] = { accden[0][0], accden[1][0], accden[2][0], accden[3][0] };

        if (cc == 1) {
            // single chunk: finalize both q32 groups directly (sole writer)
            #pragma unroll
            for (int j = 0; j < 2; ++j) {
                float* op = out + ((size_t)(bat * T_ + (q32a + j) * 32 + l16)) * 64 + qd * 4;
                #pragma unroll
                for (int g = 0; g < 2; ++g) {
                    const float rd = 1.0f / den[j * 2 + g];
                    #pragma unroll
                    for (int nt2 = 0; nt2 < 4; ++nt2) {
                        f32x4 v;
                        #pragma unroll
                        for (int i = 0; i < 4; ++i) v[i] = acc[j * 2 + g][nt2][i] * rd;
                        *(f32x4*)(op + (size_t)g * 16 * 64 + nt2 * 16) = v;
                    }
                }
            }
        } else {
            // flush: dense nt u64 stores to both deterministic slots
            #pragma unroll
            for (int j = 0; j < 2; ++j) {
                u32* np = pnum + (size_t)(slot0 + j) * 1024;
                #pragma unroll
                for (int g = 0; g < 2; ++g)
                    #pragma unroll
                    for (int nt2 = 0; nt2 < 4; ++nt2) {
                        u32 lo = (u32)f2bf(acc[j * 2 + g][nt2][0]) | ((u32)f2bf(acc[j * 2 + g][nt2][1]) << 16);
                        u32 hi = (u32)f2bf(acc[j * 2 + g][nt2][2]) | ((u32)f2bf(acc[j * 2 + g][nt2][3]) << 16);
                        u64 val = (u64)lo | ((u64)hi << 32);
                        __builtin_nontemporal_store(val, (u64*)(np + (g * 4 + nt2) * 128 + lane * 2));
                    }
            }
            if (lane < 32) {
                __builtin_nontemporal_store(den[lane >> 4],
                                            &pden[(size_t)slot0 * 32 + lane]);
                __builtin_nontemporal_store(den[2 + (lane >> 4)],
                                            &pden[(size_t)(slot0 + 1) * 32 + lane]);
            }
        }
    }
}

// ---------------------------------------------------------------------------
// Kernel 3: finalize (unchanged; CH macro drives the slot arithmetic).
// ---------------------------------------------------------------------------
__global__ __launch_bounds__(256) void fin_kernel(
    const u32* __restrict__ pnum, const float* __restrict__ pden,
    float* __restrict__ out)
{
    __shared__ float sden[8][32];
    __shared__ float rden[32];
    const int blk  = blockIdx.x;           // 0..1023
    const int xcd  = blk & 7;
    const int bat  = xcd >> 1;
    const int rest = blk >> 3;             // 0..127
    const int q32  = (rest & 63) * 2 + (xcd & 1);
    const int hh   = rest >> 6;            // h half: 0 -> h 0..31, 1 -> 32..63
    const int A = q32 >> 2, b = q32 & 3;
    const int cc = (A + CH) / CH;
    if (cc == 1) return;                   // written directly by attn
    int pre = 0;
    for (int j = 31; j > A; --j) pre += 4 * ((j + CH) / CH);
    const int base = bat * SBAT + pre + b;   // chunk ci at base + 4*ci

    // ---- parallel denominator: 8 groups, ci strided by 8 ----
    {
        const int md  = threadIdx.x & 31;
        const int grp = threadIdx.x >> 5;
        float d = 0.f;
        for (int ci = grp; ci < cc; ci += 8)
            d += pden[(size_t)(base + 4 * ci) * 32 + md];
        sden[grp][md] = d;
    }
    __syncthreads();
    if (threadIdx.x < 32) {
        float d = 0.f;
        #pragma unroll
        for (int g2 = 0; g2 < 8; ++g2) d += sden[g2][threadIdx.x];
        rden[threadIdx.x] = 1.0f / d;
    }
    __syncthreads();

    const int m   = threadIdx.x >> 3;       // out row 0..31
    const int g   = m >> 4;
    const int l16 = m & 15;
    const int h0  = hh * 32 + (threadIdx.x & 7) * 4;   // 4 h per thread
    const int nt2 = h0 >> 4;
    const int q0  = (h0 >> 2) & 3;
    const int off = (g * 4 + nt2) * 128 + q0 * 32 + l16 * 2;

    float sv0 = 0.f, sv1 = 0.f, sv2 = 0.f, sv3 = 0.f;
    const u32* sp = pnum + (size_t)base * 1024 + off;
    uint2 cur = *(const uint2*)sp;
    for (int ci = 1; ci < cc; ++ci) {
        uint2 nxt = *(const uint2*)(sp + (size_t)ci * 4096);   // next in flight
        sv0 += __uint_as_float(cur.x << 16);
        sv1 += __uint_as_float(cur.x & 0xFFFF0000u);
        sv2 += __uint_as_float(cur.y << 16);
        sv3 += __uint_as_float(cur.y & 0xFFFF0000u);
        cur = nxt;
    }
    sv0 += __uint_as_float(cur.x << 16);
    sv1 += __uint_as_float(cur.x & 0xFFFF0000u);
    sv2 += __uint_as_float(cur.y << 16);
    sv3 += __uint_as_float(cur.y & 0xFFFF0000u);

    const float rd = rden[m];
    float* op = out + (size_t)(bat * T_ + q32 * 32 + m) * 64 + h0;
    f32x4 r;
    r[0] = sv0 * rd; r[1] = sv1 * rd; r[2] = sv2 * rd; r[3] = sv3 * rd;
    *(f32x4*)op = r;
}

// ---------------------------------------------------------------------------
extern "C" void kernel_launch(void* const* d_in, const int* in_sizes, int n_in,
                              void* d_out, int out_size, void* d_ws, size_t ws_size,
                              hipStream_t stream)
{
    const float* x  = (const float*)d_in[0];
    const float* Wk = (const float*)d_in[1];
    const float* Wq = (const float*)d_in[2];
    const float* Wv = (const float*)d_in[3];
    float* out = (float*)d_out;

    u16* ws  = (u16*)d_ws;
    u16* WTf = ws;                          // 98304 u16 (padded to 131072)
    u16* Qf  = ws + 131072;                 // 1048576 u16 each
    u16* Kf  = Qf + 1048576;
    u16* Vf  = Kf + 1048576;
    u32*   pnum = (u32*)(Vf + 1048576);     // partial O (4*1088*1024 u32 reserved)
    float* pden = (float*)(pnum + (size_t)4 * 1088 * 1024);   // fixed offset

    wtrans_kernel<<<48, 256, 0, stream>>>(Wq, Wk, Wv, WTf);
    proj_kernel<<<1024, 256, 0, stream>>>(x, WTf, Qf, Kf, Vf);
    attn_kernel<<<SGRID, 256, 0, stream>>>(Qf, Kf, Vf, pnum, pden, out);
    fin_kernel<<<1024, 256, 0, stream>>>(pnum, pden, out);
}

// Round 13
// 115.407 us; speedup vs baseline: 2.7037x; 2.7037x over previous
//
#include <hip/hip_runtime.h>

typedef unsigned short u16;
typedef unsigned int u32;
typedef unsigned long long u64;
typedef __attribute__((ext_vector_type(8))) short short8;
typedef __attribute__((ext_vector_type(4))) float f32x4;

#define T_ 4096
#define QSCALE 0.18033688f   // (1/8) * log2(e): folded into Q at proj time
#define CH 4                 // key-tiles per chunk (r9 best config)
#define SBAT 576             // CH=4 slot count per bat (pnum/pden layout)
#define SGRID 288            // attn grid: 2 waves per chunk (2 q32 per wave)
#define PSTRIDE 36           // P strip row stride in u16 (72 B: 8B-aligned, bank-uniform)

#if __has_builtin(__builtin_amdgcn_exp2f)
#define EXP2F(x) __builtin_amdgcn_exp2f(x)
#else
#define EXP2F(x) exp2f(x)
#endif

__device__ __forceinline__ u16 f2bf(float f) {
    unsigned u = __float_as_uint(f);
    u += 0x7FFFu + ((u >> 16) & 1u);   // RNE to bf16
    return (u16)(u >> 16);
}

// ---------------------------------------------------------------------------
// Kernel 0: W -> WTf in MFMA-B-fragment-contiguous order.
// ---------------------------------------------------------------------------
__global__ __launch_bounds__(256) void wtrans_kernel(
    const float* __restrict__ Wq, const float* __restrict__ Wk,
    const float* __restrict__ Wv, u16* __restrict__ WTf)
{
    const int tid  = blockIdx.x * 256 + threadIdx.x;   // 48*256 = 12288
    const int frag = tid >> 6;                          // 0..191
    const int lane = tid & 63;
    const int ng   = frag >> 4;
    const int kc   = frag & 15;
    const int m    = ng >> 2;
    const float* W = (m == 0) ? Wq : (m == 1) ? Wk : Wv;
    const int h  = (ng & 3) * 16 + (lane & 15);
    const int c0 = kc * 32 + (lane >> 4) * 8;
    short8 v;
    #pragma unroll
    for (int j = 0; j < 8; ++j)
        v[j] = (short)f2bf(W[(c0 + j) * 64 + h]);
    *(short8*)(WTf + (size_t)frag * 512 + lane * 8) = v;
}

// ---------------------------------------------------------------------------
// Kernel 1: projection. (Unchanged.)
// ---------------------------------------------------------------------------
__global__ __launch_bounds__(256) void proj_kernel(
    const float* __restrict__ x, const u16* __restrict__ WTf,
    u16* __restrict__ Qf, u16* __restrict__ Kf, u16* __restrict__ Vf)
{
    __shared__ u16 xs[16 * 520];
    __shared__ u16 img[3072];   // Q @0, K @1024, V @2048 (u16 units)
    const int t    = threadIdx.x;
    const int lane = t & 63;
    const int w    = t >> 6;
    const int l16  = lane & 15;
    const int quad = lane >> 4;
    const int rowbase = blockIdx.x * 16;
    const int bat  = rowbase >> 12;
    const int tloc = rowbase & 4095;

    #pragma unroll
    for (int it = 0; it < 8; ++it) {
        int f   = t + it * 256;                 // float4 index, coalesced
        int row = f >> 7;
        int c4  = (f & 127) * 4;
        f32x4 a = *(const f32x4*)(x + (size_t)(rowbase + row) * 512 + c4);
        unsigned lo = (unsigned)f2bf(a[0]) | ((unsigned)f2bf(a[1]) << 16);
        unsigned hi = (unsigned)f2bf(a[2]) | ((unsigned)f2bf(a[3]) << 16);
        *(uint2*)(xs + row * 520 + c4) = make_uint2(lo, hi);
    }
    __syncthreads();

    f32x4 acc[3];
    #pragma unroll
    for (int nt = 0; nt < 3; ++nt) acc[nt] = (f32x4){0.f, 0.f, 0.f, 0.f};

    const u16* ab = xs + l16 * 520 + quad * 8;
    const u16* wb = WTf + (size_t)(w * 3 * 16) * 512 + lane * 8;

    #pragma unroll 4
    for (int kc = 0; kc < 16; ++kc) {
        short8 af = *(const short8*)(ab + kc * 32);
        #pragma unroll
        for (int nt = 0; nt < 3; ++nt) {
            short8 bf = *(const short8*)(wb + (size_t)(nt * 16 + kc) * 512);
            acc[nt] = __builtin_amdgcn_mfma_f32_16x16x32_bf16(af, bf, acc[nt], 0, 0, 0);
        }
    }

    // ---- epilogue: scatter into LDS image ----
    #pragma unroll
    for (int nt = 0; nt < 3; ++nt) {
        int ng = w * 3 + nt;
        if (ng < 8) {
            int ng4  = ng & 3;
            float sc = (ng < 4) ? QSCALE : 1.0f;
            u16* ib  = img + ((ng < 4) ? 0 : 1024) + (ng4 >> 1) * 512
                          + ((ng4 & 1) * 2 + (l16 >> 3)) * 128 + (l16 & 7);
            #pragma unroll
            for (int i = 0; i < 4; ++i)
                ib[(quad * 4 + i) * 8] = f2bf(acc[nt][i] * sc);
        } else {
            int nt2  = ng - 8;
            unsigned lo = (unsigned)f2bf(acc[nt][0]) | ((unsigned)f2bf(acc[nt][1]) << 16);
            unsigned hi = (unsigned)f2bf(acc[nt][2]) | ((unsigned)f2bf(acc[nt][3]) << 16);
            *(uint2*)(img + 2048 + nt2 * 256 + (quad >> 1) * 128 + l16 * 8
                          + (quad & 1) * 4) = make_uint2(lo, hi);
        }
    }
    __syncthreads();

    // ---- coalesced copy-out ----
    const int tb   = tloc >> 4;
    const int kt   = tloc >> 7;
    const int ks   = (tloc >> 5) & 3;
    const int half = (tloc >> 4) & 1;
    uint2 vq = *(uint2*)(img + t * 4);
    uint2 vk = *(uint2*)(img + 1024 + t * 4);
    uint2 vv = *(uint2*)(img + 2048 + t * 4);
    *(uint2*)(Qf + (size_t)(bat * 256 + tb) * 1024 + t * 4) = vq;
    *(uint2*)(Kf + (size_t)(bat * 256 + tb) * 1024 + t * 4) = vk;
    const int nt2c = t >> 6;
    *(uint2*)(Vf + (size_t)((bat * 32 + kt) * 4 + ks) * 2048
                 + nt2c * 512 + half * 256 + (t & 63) * 4) = vv;
}

// ---------------------------------------------------------------------------
// Kernel 2: attention — r9 config (CH=4, gg=4) + 1-step-ahead K prefetch
// and head-of-step V loads (r11 counters: latency-bound, MfmaUtil 8%,
// VALUBusy 8%, Occ 11%, 0 bank conflicts — the naked same-step K-load ->
// QK-MFMA chain was the binder). Every load now has >= 1 full step of
// issue work to land. Successor prefetch is static & in-workspace (worst
// case reads the first bytes of Vf; discarded). Accumulation order
// unchanged -> bit-identical output (absmax 0.0007324219).
// ---------------------------------------------------------------------------
__global__ __launch_bounds__(256, 2) void attn_kernel(
    const u16* __restrict__ Qf, const u16* __restrict__ Kf,
    const u16* __restrict__ Vf, u32* __restrict__ pnum,
    float* __restrict__ pden, float* __restrict__ out)
{
    __shared__ u16 Ps[4][2][4][16 * PSTRIDE];   // [wave][par][gg][...], 36.9 KB

    const int w    = threadIdx.x >> 6;
    const int lane = threadIdx.x & 63;
    const int l16  = lane & 15;
    const int qd   = lane >> 4;
    const int xcd  = blockIdx.x & 7;
    const int bat  = xcd >> 1;
    const int tw   = ((blockIdx.x >> 3) * 2 + (xcd & 1)) * 4 + w;  // 0..287

    int A = 31, pre = 0, cc = 1;
    for (;;) {                               // big-A first; pre counts 2 tasks/chunk
        cc = (A + CH) / CH;
        int cnt2 = 2 * cc;
        if (tw < pre + cnt2) break;
        pre += cnt2; --A;
    }
    const int r    = tw - pre;
    const int c    = r >> 1;                 // my chunk (shared by 2 waves)
    const int bp   = r & 1;                  // q32-pair index: q32 = 4A+2bp+{0,1}
    const int nkt  = A + 1;
    const int q32a = 4 * A + 2 * bp;
    const int kt0  = c * CH;
    const int kt1  = min(kt0 + CH, nkt);
    const int slot0 = bat * SBAT + 2 * pre + 2 * bp + 4 * c;   // j=0; j=1 at +1

    short8 aq[4][2];                         // gg = j*2 + g
    #pragma unroll
    for (int gg = 0; gg < 4; ++gg)
        #pragma unroll
        for (int f = 0; f < 2; ++f)
            aq[gg][f] = *(const short8*)(Qf
                + ((size_t)((bat * 256 + (q32a + (gg >> 1)) * 2 + (gg & 1)) * 2 + f)) * 512 + lane * 8);

    // constant-ones A-fragment for the den MFMA (bf16 1.0 = 0x3F80)
    short8 ones;
    #pragma unroll
    for (int j = 0; j < 8; ++j) ones[j] = (short)0x3F80;

    f32x4 acc[4][4];
    f32x4 accden[4];
    #pragma unroll
    for (int gg = 0; gg < 4; ++gg) {
        accden[gg] = (f32x4){0.f, 0.f, 0.f, 0.f};
        #pragma unroll
        for (int n = 0; n < 4; ++n) acc[gg][n] = (f32x4){0.f, 0.f, 0.f, 0.f};
    }

    u16* Psw = &Ps[w][0][0][0];    // par stride 2304 u16, gg stride 576
    int par = 0;

    // per-wave K/V bases; key-tile stride = 8192 u16 in both arrays
    const u16* kbase = Kf + ((size_t)(bat * 256 + kt0 * 8) * 2) * 512 + lane * 8;
    const u16* vbase = Vf + ((size_t)((bat * 32 + kt0) * 16)) * 512 + lane * 8;

    // pipeline registers
    short8 kc[4];      // K frags for current step (prefetched last step)
    short8 avp[4];     // V frags of previous step (consumed in (b))
    short8 app[4];     // P strips of previous step (consumed in (b))

    // prologue: K for step (dt=0, ks=0)
    kc[0] = *(const short8*)(kbase);
    kc[1] = *(const short8*)(kbase + 512);
    kc[2] = *(const short8*)(kbase + 1024);
    kc[3] = *(const short8*)(kbase + 1536);

    auto step = [&](int dt, int ks, bool first) __attribute__((always_inline)) {
        // ---- (a) issue next-step K prefetch + current-step V loads ----
        const int ndt = (ks == 3) ? dt + 1 : dt;
        const int nks = (ks == 3) ? 0 : ks + 1;
        short8 kn[4];
        {
            const u16* kb2 = kbase + ndt * 8192 + (size_t)(2 * nks) * 1024;
            kn[0] = *(const short8*)(kb2);
            kn[1] = *(const short8*)(kb2 + 512);
            kn[2] = *(const short8*)(kb2 + 1024);
            kn[3] = *(const short8*)(kb2 + 1536);
        }
        short8 avc[4];
        {
            const u16* vb2 = vbase + dt * 8192 + (size_t)(ks * 4) * 512;
            avc[0] = *(const short8*)(vb2);
            avc[1] = *(const short8*)(vb2 + 512);
            avc[2] = *(const short8*)(vb2 + 1024);
            avc[3] = *(const short8*)(vb2 + 1536);
        }
        // ---- (a1) QK MFMAs on prefetched kc ----
        f32x4 st[2][4];
        #pragma unroll
        for (int b = 0; b < 2; ++b) {
            #pragma unroll
            for (int gg = 0; gg < 4; ++gg) {
                f32x4 s = (f32x4){0.f, 0.f, 0.f, 0.f};
                s = __builtin_amdgcn_mfma_f32_16x16x32_bf16(kc[b * 2],     aq[gg][0], s, 0, 0, 0);
                s = __builtin_amdgcn_mfma_f32_16x16x32_bf16(kc[b * 2 + 1], aq[gg][1], s, 0, 0, 0);
                st[b][gg] = s;
            }
        }
        // ---- (b) den + PV MFMAs for the PREVIOUS step ----
        if (!first) {
            #pragma unroll
            for (int gg = 0; gg < 4; ++gg)
                accden[gg] = __builtin_amdgcn_mfma_f32_16x16x32_bf16(ones, app[gg], accden[gg], 0, 0, 0);
            #pragma unroll
            for (int nt2 = 0; nt2 < 4; ++nt2)
                #pragma unroll
                for (int gg = 0; gg < 4; ++gg)
                    acc[gg][nt2] = __builtin_amdgcn_mfma_f32_16x16x32_bf16(avp[nt2], app[gg], acc[gg][nt2], 0, 0, 0);
        }
        // ---- (c) exp -> pack -> strip write (parity par) ----
        u16* sw = Psw + par * 2304;
        #pragma unroll
        for (int b = 0; b < 2; ++b) {
            #pragma unroll
            for (int gg = 0; gg < 4; ++gg) {
                f32x4 s = st[b][gg];
                float p0 = EXP2F(s[0]);
                float p1 = EXP2F(s[1]);
                float p2 = EXP2F(s[2]);
                float p3 = EXP2F(s[3]);
                u32 q01 = __builtin_amdgcn_perm(__float_as_uint(p1), __float_as_uint(p0), 0x07060302u);
                u32 q23 = __builtin_amdgcn_perm(__float_as_uint(p3), __float_as_uint(p2), 0x07060302u);
                u64 pv = (u64)q01 | ((u64)q23 << 32);
                *(u64*)(sw + gg * 576 + l16 * PSTRIDE + b * 16 + qd * 4) = pv;
            }
        }
        // ---- (d) strip reads for the current step ----
        short8 apc[4];
        #pragma unroll
        for (int gg = 0; gg < 4; ++gg)
            apc[gg] = *(const short8*)(sw + gg * 576 + l16 * PSTRIDE + qd * 8);
        // ---- rotate pipeline registers ----
        #pragma unroll
        for (int i = 0; i < 4; ++i) {
            kc[i]  = kn[i];
            avp[i] = avc[i];
            app[i] = apc[i];
        }
        par ^= 1;
    };

    auto body = [&](int dt, bool firstb) __attribute__((always_inline)) {
        step(dt, 0, firstb);
        step(dt, 1, false);
        step(dt, 2, false);
        step(dt, 3, false);
    };

    // straight-line the <=4 key-tile iterations (no dynamic loop)
    body(0, true);
    if (kt0 + 1 < kt1) body(1, false);
    if (kt0 + 2 < kt1) body(2, false);
    if (kt0 + 3 < kt1) body(3, false);

    // ---- drain: den + PV for the final step ----
    #pragma unroll
    for (int gg = 0; gg < 4; ++gg)
        accden[gg] = __builtin_amdgcn_mfma_f32_16x16x32_bf16(ones, app[gg], accden[gg], 0, 0, 0);
    #pragma unroll
    for (int nt2 = 0; nt2 < 4; ++nt2)
        #pragma unroll
        for (int gg = 0; gg < 4; ++gg)
            acc[gg][nt2] = __builtin_amdgcn_mfma_f32_16x16x32_bf16(avp[nt2], app[gg], acc[gg][nt2], 0, 0, 0);

    // den is replicated across rows by the ones-MFMA: lane-local, no reduce
    float den[4] = { accden[0][0], accden[1][0], accden[2][0], accden[3][0] };

    if (cc == 1) {
        // single chunk: finalize both q32 groups directly (sole writer)
        #pragma unroll
        for (int j = 0; j < 2; ++j) {
            float* op = out + ((size_t)(bat * T_ + (q32a + j) * 32 + l16)) * 64 + qd * 4;
            #pragma unroll
            for (int g = 0; g < 2; ++g) {
                const float rd = 1.0f / den[j * 2 + g];
                #pragma unroll
                for (int nt2 = 0; nt2 < 4; ++nt2) {
                    f32x4 v;
                    #pragma unroll
                    for (int i = 0; i < 4; ++i) v[i] = acc[j * 2 + g][nt2][i] * rd;
                    *(f32x4*)(op + (size_t)g * 16 * 64 + nt2 * 16) = v;
                }
            }
        }
    } else {
        // flush: dense nt u64 stores to both deterministic slots
        #pragma unroll
        for (int j = 0; j < 2; ++j) {
            u32* np = pnum + (size_t)(slot0 + j) * 1024;
            #pragma unroll
            for (int g = 0; g < 2; ++g)
                #pragma unroll
                for (int nt2 = 0; nt2 < 4; ++nt2) {
                    u32 lo = (u32)f2bf(acc[j * 2 + g][nt2][0]) | ((u32)f2bf(acc[j * 2 + g][nt2][1]) << 16);
                    u32 hi = (u32)f2bf(acc[j * 2 + g][nt2][2]) | ((u32)f2bf(acc[j * 2 + g][nt2][3]) << 16);
                    u64 val = (u64)lo | ((u64)hi << 32);
                    __builtin_nontemporal_store(val, (u64*)(np + (g * 4 + nt2) * 128 + lane * 2));
                }
        }
        if (lane < 32) {
            __builtin_nontemporal_store(den[lane >> 4],
                                        &pden[(size_t)slot0 * 32 + lane]);
            __builtin_nontemporal_store(den[2 + (lane >> 4)],
                                        &pden[(size_t)(slot0 + 1) * 32 + lane]);
        }
    }
}

// ---------------------------------------------------------------------------
// Kernel 3: finalize (unchanged; CH macro drives the slot arithmetic).
// ---------------------------------------------------------------------------
__global__ __launch_bounds__(256) void fin_kernel(
    const u32* __restrict__ pnum, const float* __restrict__ pden,
    float* __restrict__ out)
{
    __shared__ float sden[8][32];
    __shared__ float rden[32];
    const int blk  = blockIdx.x;           // 0..1023
    const int xcd  = blk & 7;
    const int bat  = xcd >> 1;
    const int rest = blk >> 3;             // 0..127
    const int q32  = (rest & 63) * 2 + (xcd & 1);
    const int hh   = rest >> 6;            // h half: 0 -> h 0..31, 1 -> 32..63
    const int A = q32 >> 2, b = q32 & 3;
    const int cc = (A + CH) / CH;
    if (cc == 1) return;                   // written directly by attn
    int pre = 0;
    for (int j = 31; j > A; --j) pre += 4 * ((j + CH) / CH);
    const int base = bat * SBAT + pre + b;   // chunk ci at base + 4*ci

    // ---- parallel denominator: 8 groups, ci strided by 8 ----
    {
        const int md  = threadIdx.x & 31;
        const int grp = threadIdx.x >> 5;
        float d = 0.f;
        for (int ci = grp; ci < cc; ci += 8)
            d += pden[(size_t)(base + 4 * ci) * 32 + md];
        sden[grp][md] = d;
    }
    __syncthreads();
    if (threadIdx.x < 32) {
        float d = 0.f;
        #pragma unroll
        for (int g2 = 0; g2 < 8; ++g2) d += sden[g2][threadIdx.x];
        rden[threadIdx.x] = 1.0f / d;
    }
    __syncthreads();

    const int m   = threadIdx.x >> 3;       // out row 0..31
    const int g   = m >> 4;
    const int l16 = m & 15;
    const int h0  = hh * 32 + (threadIdx.x & 7) * 4;   // 4 h per thread
    const int nt2 = h0 >> 4;
    const int q0  = (h0 >> 2) & 3;
    const int off = (g * 4 + nt2) * 128 + q0 * 32 + l16 * 2;

    float sv0 = 0.f, sv1 = 0.f, sv2 = 0.f, sv3 = 0.f;
    const u32* sp = pnum + (size_t)base * 1024 + off;
    uint2 cur = *(const uint2*)sp;
    for (int ci = 1; ci < cc; ++ci) {
        uint2 nxt = *(const uint2*)(sp + (size_t)ci * 4096);   // next in flight
        sv0 += __uint_as_float(cur.x << 16);
        sv1 += __uint_as_float(cur.x & 0xFFFF0000u);
        sv2 += __uint_as_float(cur.y << 16);
        sv3 += __uint_as_float(cur.y & 0xFFFF0000u);
        cur = nxt;
    }
    sv0 += __uint_as_float(cur.x << 16);
    sv1 += __uint_as_float(cur.x & 0xFFFF0000u);
    sv2 += __uint_as_float(cur.y << 16);
    sv3 += __uint_as_float(cur.y & 0xFFFF0000u);

    const float rd = rden[m];
    float* op = out + (size_t)(bat * T_ + q32 * 32 + m) * 64 + h0;
    f32x4 r;
    r[0] = sv0 * rd; r[1] = sv1 * rd; r[2] = sv2 * rd; r[3] = sv3 * rd;
    *(f32x4*)op = r;
}

// ---------------------------------------------------------------------------
extern "C" void kernel_launch(void* const* d_in, const int* in_sizes, int n_in,
                              void* d_out, int out_size, void* d_ws, size_t ws_size,
                              hipStream_t stream)
{
    const float* x  = (const float*)d_in[0];
    const float* Wk = (const float*)d_in[1];
    const float* Wq = (const float*)d_in[2];
    const float* Wv = (const float*)d_in[3];
    float* out = (float*)d_out;

    u16* ws  = (u16*)d_ws;
    u16* WTf = ws;                          // 98304 u16 (padded to 131072)
    u16* Qf  = ws + 131072;                 // 1048576 u16 each
    u16* Kf  = Qf + 1048576;
    u16* Vf  = Kf + 1048576;
    u32*   pnum = (u32*)(Vf + 1048576);     // partial O (4*1088*1024 u32 reserved)
    float* pden = (float*)(pnum + (size_t)4 * 1088 * 1024);   // fixed offset

    wtrans_kernel<<<48, 256, 0, stream>>>(Wq, Wk, Wv, WTf);
    proj_kernel<<<1024, 256, 0, stream>>>(x, WTf, Qf, Kf, Vf);
    attn_kernel<<<SGRID, 256, 0, stream>>>(Qf, Kf, Vf, pnum, pden, out);
    fin_kernel<<<1024, 256, 0, stream>>>(pnum, pden, out);
}

// Round 14
// 114.142 us; speedup vs baseline: 2.7336x; 1.0111x over previous
//
#include <hip/hip_runtime.h>

typedef unsigned short u16;
typedef unsigned int u32;
typedef unsigned long long u64;
typedef __attribute__((ext_vector_type(8))) short short8;
typedef __attribute__((ext_vector_type(4))) float f32x4;

#define T_ 4096
#define QSCALE 0.18033688f   // (1/8) * log2(e): folded into Q at proj time
#define CH 4                 // key-tiles per chunk (r9 best config)
#define SBAT 576             // CH=4 slot count per bat (pnum/pden layout)
#define SGRID 288            // attn grid: 2 waves per chunk (2 q32 per wave)
#define PSTRIDE 36           // P strip row stride in u16 (72 B: 8B-aligned, bank-uniform)

#if __has_builtin(__builtin_amdgcn_exp2f)
#define EXP2F(x) __builtin_amdgcn_exp2f(x)
#else
#define EXP2F(x) exp2f(x)
#endif

__device__ __forceinline__ u16 f2bf(float f) {
    unsigned u = __float_as_uint(f);
    u += 0x7FFFu + ((u >> 16) & 1u);   // RNE to bf16
    return (u16)(u >> 16);
}

// ---------------------------------------------------------------------------
// Kernel 0: W -> WTf in MFMA-B-fragment-contiguous order.
// ---------------------------------------------------------------------------
__global__ __launch_bounds__(256) void wtrans_kernel(
    const float* __restrict__ Wq, const float* __restrict__ Wk,
    const float* __restrict__ Wv, u16* __restrict__ WTf)
{
    const int tid  = blockIdx.x * 256 + threadIdx.x;   // 48*256 = 12288
    const int frag = tid >> 6;                          // 0..191
    const int lane = tid & 63;
    const int ng   = frag >> 4;
    const int kc   = frag & 15;
    const int m    = ng >> 2;
    const float* W = (m == 0) ? Wq : (m == 1) ? Wk : Wv;
    const int h  = (ng & 3) * 16 + (lane & 15);
    const int c0 = kc * 32 + (lane >> 4) * 8;
    short8 v;
    #pragma unroll
    for (int j = 0; j < 8; ++j)
        v[j] = (short)f2bf(W[(c0 + j) * 64 + h]);
    *(short8*)(WTf + (size_t)frag * 512 + lane * 8) = v;
}

// ---------------------------------------------------------------------------
// Kernel 1: projection. (Unchanged.)
// ---------------------------------------------------------------------------
__global__ __launch_bounds__(256) void proj_kernel(
    const float* __restrict__ x, const u16* __restrict__ WTf,
    u16* __restrict__ Qf, u16* __restrict__ Kf, u16* __restrict__ Vf)
{
    __shared__ u16 xs[16 * 520];
    __shared__ u16 img[3072];   // Q @0, K @1024, V @2048 (u16 units)
    const int t    = threadIdx.x;
    const int lane = t & 63;
    const int w    = t >> 6;
    const int l16  = lane & 15;
    const int quad = lane >> 4;
    const int rowbase = blockIdx.x * 16;
    const int bat  = rowbase >> 12;
    const int tloc = rowbase & 4095;

    #pragma unroll
    for (int it = 0; it < 8; ++it) {
        int f   = t + it * 256;                 // float4 index, coalesced
        int row = f >> 7;
        int c4  = (f & 127) * 4;
        f32x4 a = *(const f32x4*)(x + (size_t)(rowbase + row) * 512 + c4);
        unsigned lo = (unsigned)f2bf(a[0]) | ((unsigned)f2bf(a[1]) << 16);
        unsigned hi = (unsigned)f2bf(a[2]) | ((unsigned)f2bf(a[3]) << 16);
        *(uint2*)(xs + row * 520 + c4) = make_uint2(lo, hi);
    }
    __syncthreads();

    f32x4 acc[3];
    #pragma unroll
    for (int nt = 0; nt < 3; ++nt) acc[nt] = (f32x4){0.f, 0.f, 0.f, 0.f};

    const u16* ab = xs + l16 * 520 + quad * 8;
    const u16* wb = WTf + (size_t)(w * 3 * 16) * 512 + lane * 8;

    #pragma unroll 4
    for (int kc = 0; kc < 16; ++kc) {
        short8 af = *(const short8*)(ab + kc * 32);
        #pragma unroll
        for (int nt = 0; nt < 3; ++nt) {
            short8 bf = *(const short8*)(wb + (size_t)(nt * 16 + kc) * 512);
            acc[nt] = __builtin_amdgcn_mfma_f32_16x16x32_bf16(af, bf, acc[nt], 0, 0, 0);
        }
    }

    // ---- epilogue: scatter into LDS image ----
    #pragma unroll
    for (int nt = 0; nt < 3; ++nt) {
        int ng = w * 3 + nt;
        if (ng < 8) {
            int ng4  = ng & 3;
            float sc = (ng < 4) ? QSCALE : 1.0f;
            u16* ib  = img + ((ng < 4) ? 0 : 1024) + (ng4 >> 1) * 512
                          + ((ng4 & 1) * 2 + (l16 >> 3)) * 128 + (l16 & 7);
            #pragma unroll
            for (int i = 0; i < 4; ++i)
                ib[(quad * 4 + i) * 8] = f2bf(acc[nt][i] * sc);
        } else {
            int nt2  = ng - 8;
            unsigned lo = (unsigned)f2bf(acc[nt][0]) | ((unsigned)f2bf(acc[nt][1]) << 16);
            unsigned hi = (unsigned)f2bf(acc[nt][2]) | ((unsigned)f2bf(acc[nt][3]) << 16);
            *(uint2*)(img + 2048 + nt2 * 256 + (quad >> 1) * 128 + l16 * 8
                          + (quad & 1) * 4) = make_uint2(lo, hi);
        }
    }
    __syncthreads();

    // ---- coalesced copy-out ----
    const int tb   = tloc >> 4;
    const int kt   = tloc >> 7;
    const int ks   = (tloc >> 5) & 3;
    const int half = (tloc >> 4) & 1;
    uint2 vq = *(uint2*)(img + t * 4);
    uint2 vk = *(uint2*)(img + 1024 + t * 4);
    uint2 vv = *(uint2*)(img + 2048 + t * 4);
    *(uint2*)(Qf + (size_t)(bat * 256 + tb) * 1024 + t * 4) = vq;
    *(uint2*)(Kf + (size_t)(bat * 256 + tb) * 1024 + t * 4) = vk;
    const int nt2c = t >> 6;
    *(uint2*)(Vf + (size_t)((bat * 32 + kt) * 4 + ks) * 2048
                 + nt2c * 512 + half * 256 + (t & 63) * 4) = vv;
}

// ---------------------------------------------------------------------------
// Kernel 2: attention — FINAL: exact r9 configuration (best measured,
// 114.55 us). CH=4, 2 q32-groups per wave (gg=4: every K/V fragment feeds
// 4 MFMAs), 1-deep software pipeline on P-strips and V (consumed one step
// after production). K-prefetch (r13) and further pipelining measured
// neutral; r11 counters showed all pipes <11% busy — latency-bound under
// an ~85us harness fill floor. Accumulation order preserved across all
// rounds -> absmax bit-exact 0.0007324219.
// ---------------------------------------------------------------------------
__global__ __launch_bounds__(256, 2) void attn_kernel(
    const u16* __restrict__ Qf, const u16* __restrict__ Kf,
    const u16* __restrict__ Vf, u32* __restrict__ pnum,
    float* __restrict__ pden, float* __restrict__ out)
{
    __shared__ u16 Ps[4][2][4][16 * PSTRIDE];   // [wave][par][gg][...], 36.9 KB

    const int w    = threadIdx.x >> 6;
    const int lane = threadIdx.x & 63;
    const int l16  = lane & 15;
    const int qd   = lane >> 4;
    const int xcd  = blockIdx.x & 7;
    const int bat  = xcd >> 1;
    const int tw   = ((blockIdx.x >> 3) * 2 + (xcd & 1)) * 4 + w;  // 0..287

    int A = 31, pre = 0, cc = 1;
    for (;;) {                               // big-A first; pre counts 2 tasks/chunk
        cc = (A + CH) / CH;
        int cnt2 = 2 * cc;
        if (tw < pre + cnt2) break;
        pre += cnt2; --A;
    }
    const int r    = tw - pre;
    const int c    = r >> 1;                 // my chunk (shared by 2 waves)
    const int bp   = r & 1;                  // q32-pair index: q32 = 4A+2bp+{0,1}
    const int nkt  = A + 1;
    const int q32a = 4 * A + 2 * bp;
    const int kt0  = c * CH;
    const int kt1  = min(kt0 + CH, nkt);
    const int slot0 = bat * SBAT + 2 * pre + 2 * bp + 4 * c;   // j=0; j=1 at +1

    short8 aq[4][2];                         // gg = j*2 + g
    #pragma unroll
    for (int gg = 0; gg < 4; ++gg)
        #pragma unroll
        for (int f = 0; f < 2; ++f)
            aq[gg][f] = *(const short8*)(Qf
                + ((size_t)((bat * 256 + (q32a + (gg >> 1)) * 2 + (gg & 1)) * 2 + f)) * 512 + lane * 8);

    // constant-ones A-fragment for the den MFMA (bf16 1.0 = 0x3F80)
    short8 ones;
    #pragma unroll
    for (int j = 0; j < 8; ++j) ones[j] = (short)0x3F80;

    f32x4 acc[4][4];
    f32x4 accden[4];
    #pragma unroll
    for (int gg = 0; gg < 4; ++gg) {
        accden[gg] = (f32x4){0.f, 0.f, 0.f, 0.f};
        #pragma unroll
        for (int n = 0; n < 4; ++n) acc[gg][n] = (f32x4){0.f, 0.f, 0.f, 0.f};
    }

    u16* Psw = &Ps[w][0][0][0];    // par stride 2304 u16, gg stride 576
    int par = 0;

    // pipeline registers (consumed one step after they are produced)
    short8 ap_prev[4];
    short8 av_prev[4];

    auto step = [&](int kt, int ks, bool first) __attribute__((always_inline)) {
        const u16* kfb = Kf + ((size_t)(bat * 256 + kt * 8) * 2) * 512 + lane * 8;
        const u16* vfb = Vf + ((size_t)((bat * 32 + kt) * 16)) * 512 + lane * 8;
        // ---- (a) K loads + QK MFMAs -> st regs (each K frag feeds 4 gg) ----
        f32x4 st[2][4];
        #pragma unroll
        for (int b = 0; b < 2; ++b) {
            short8 k0 = *(const short8*)(kfb + (size_t)(2 * ks + b) * 1024);
            short8 k1 = *(const short8*)(kfb + (size_t)(2 * ks + b) * 1024 + 512);
            #pragma unroll
            for (int gg = 0; gg < 4; ++gg) {
                f32x4 s = (f32x4){0.f, 0.f, 0.f, 0.f};
                s = __builtin_amdgcn_mfma_f32_16x16x32_bf16(k0, aq[gg][0], s, 0, 0, 0);
                s = __builtin_amdgcn_mfma_f32_16x16x32_bf16(k1, aq[gg][1], s, 0, 0, 0);
                st[b][gg] = s;
            }
        }
        // ---- (b) den + PV MFMAs for the PREVIOUS step (latency hidden) ----
        if (!first) {
            #pragma unroll
            for (int gg = 0; gg < 4; ++gg)
                accden[gg] = __builtin_amdgcn_mfma_f32_16x16x32_bf16(ones, ap_prev[gg], accden[gg], 0, 0, 0);
            #pragma unroll
            for (int nt2 = 0; nt2 < 4; ++nt2)
                #pragma unroll
                for (int gg = 0; gg < 4; ++gg)
                    acc[gg][nt2] = __builtin_amdgcn_mfma_f32_16x16x32_bf16(av_prev[nt2], ap_prev[gg], acc[gg][nt2], 0, 0, 0);
        }
        // ---- (c) exp -> pack -> strip write (parity par) ----
        u16* sw = Psw + par * 2304;
        #pragma unroll
        for (int b = 0; b < 2; ++b) {
            #pragma unroll
            for (int gg = 0; gg < 4; ++gg) {
                f32x4 s = st[b][gg];
                float p0 = EXP2F(s[0]);
                float p1 = EXP2F(s[1]);
                float p2 = EXP2F(s[2]);
                float p3 = EXP2F(s[3]);
                u32 q01 = __builtin_amdgcn_perm(__float_as_uint(p1), __float_as_uint(p0), 0x07060302u);
                u32 q23 = __builtin_amdgcn_perm(__float_as_uint(p3), __float_as_uint(p2), 0x07060302u);
                u64 pv = (u64)q01 | ((u64)q23 << 32);
                *(u64*)(sw + gg * 576 + l16 * PSTRIDE + b * 16 + qd * 4) = pv;
            }
        }
        // ---- (d) issue next-step consumables: V loads + strip reads ----
        #pragma unroll
        for (int nt2 = 0; nt2 < 4; ++nt2)
            av_prev[nt2] = *(const short8*)(vfb + (size_t)(ks * 4 + nt2) * 512);
        #pragma unroll
        for (int gg = 0; gg < 4; ++gg)
            ap_prev[gg] = *(const short8*)(sw + gg * 576 + l16 * PSTRIDE + qd * 8);
        par ^= 1;
    };

    auto body = [&](int kt, bool firstb) __attribute__((always_inline)) {
        step(kt, 0, firstb);
        step(kt, 1, false);
        step(kt, 2, false);
        step(kt, 3, false);
    };

    // straight-line the <=4 key-tile iterations (no dynamic loop)
    body(kt0, true);
    if (kt0 + 1 < kt1) body(kt0 + 1, false);
    if (kt0 + 2 < kt1) body(kt0 + 2, false);
    if (kt0 + 3 < kt1) body(kt0 + 3, false);

    // ---- drain: den + PV for the final step ----
    #pragma unroll
    for (int gg = 0; gg < 4; ++gg)
        accden[gg] = __builtin_amdgcn_mfma_f32_16x16x32_bf16(ones, ap_prev[gg], accden[gg], 0, 0, 0);
    #pragma unroll
    for (int nt2 = 0; nt2 < 4; ++nt2)
        #pragma unroll
        for (int gg = 0; gg < 4; ++gg)
            acc[gg][nt2] = __builtin_amdgcn_mfma_f32_16x16x32_bf16(av_prev[nt2], ap_prev[gg], acc[gg][nt2], 0, 0, 0);

    // den is replicated across rows by the ones-MFMA: lane-local, no reduce
    float den[4] = { accden[0][0], accden[1][0], accden[2][0], accden[3][0] };

    if (cc == 1) {
        // single chunk: finalize both q32 groups directly (sole writer)
        #pragma unroll
        for (int j = 0; j < 2; ++j) {
            float* op = out + ((size_t)(bat * T_ + (q32a + j) * 32 + l16)) * 64 + qd * 4;
            #pragma unroll
            for (int g = 0; g < 2; ++g) {
                const float rd = 1.0f / den[j * 2 + g];
                #pragma unroll
                for (int nt2 = 0; nt2 < 4; ++nt2) {
                    f32x4 v;
                    #pragma unroll
                    for (int i = 0; i < 4; ++i) v[i] = acc[j * 2 + g][nt2][i] * rd;
                    *(f32x4*)(op + (size_t)g * 16 * 64 + nt2 * 16) = v;
                }
            }
        }
    } else {
        // flush: dense nt u64 stores to both deterministic slots
        #pragma unroll
        for (int j = 0; j < 2; ++j) {
            u32* np = pnum + (size_t)(slot0 + j) * 1024;
            #pragma unroll
            for (int g = 0; g < 2; ++g)
                #pragma unroll
                for (int nt2 = 0; nt2 < 4; ++nt2) {
                    u32 lo = (u32)f2bf(acc[j * 2 + g][nt2][0]) | ((u32)f2bf(acc[j * 2 + g][nt2][1]) << 16);
                    u32 hi = (u32)f2bf(acc[j * 2 + g][nt2][2]) | ((u32)f2bf(acc[j * 2 + g][nt2][3]) << 16);
                    u64 val = (u64)lo | ((u64)hi << 32);
                    __builtin_nontemporal_store(val, (u64*)(np + (g * 4 + nt2) * 128 + lane * 2));
                }
        }
        if (lane < 32) {
            __builtin_nontemporal_store(den[lane >> 4],
                                        &pden[(size_t)slot0 * 32 + lane]);
            __builtin_nontemporal_store(den[2 + (lane >> 4)],
                                        &pden[(size_t)(slot0 + 1) * 32 + lane]);
        }
    }
}

// ---------------------------------------------------------------------------
// Kernel 3: finalize (unchanged; CH macro drives the slot arithmetic).
// ---------------------------------------------------------------------------
__global__ __launch_bounds__(256) void fin_kernel(
    const u32* __restrict__ pnum, const float* __restrict__ pden,
    float* __restrict__ out)
{
    __shared__ float sden[8][32];
    __shared__ float rden[32];
    const int blk  = blockIdx.x;           // 0..1023
    const int xcd  = blk & 7;
    const int bat  = xcd >> 1;
    const int rest = blk >> 3;             // 0..127
    const int q32  = (rest & 63) * 2 + (xcd & 1);
    const int hh   = rest >> 6;            // h half: 0 -> h 0..31, 1 -> 32..63
    const int A = q32 >> 2, b = q32 & 3;
    const int cc = (A + CH) / CH;
    if (cc == 1) return;                   // written directly by attn
    int pre = 0;
    for (int j = 31; j > A; --j) pre += 4 * ((j + CH) / CH);
    const int base = bat * SBAT + pre + b;   // chunk ci at base + 4*ci

    // ---- parallel denominator: 8 groups, ci strided by 8 ----
    {
        const int md  = threadIdx.x & 31;
        const int grp = threadIdx.x >> 5;
        float d = 0.f;
        for (int ci = grp; ci < cc; ci += 8)
            d += pden[(size_t)(base + 4 * ci) * 32 + md];
        sden[grp][md] = d;
    }
    __syncthreads();
    if (threadIdx.x < 32) {
        float d = 0.f;
        #pragma unroll
        for (int g2 = 0; g2 < 8; ++g2) d += sden[g2][threadIdx.x];
        rden[threadIdx.x] = 1.0f / d;
    }
    __syncthreads();

    const int m   = threadIdx.x >> 3;       // out row 0..31
    const int g   = m >> 4;
    const int l16 = m & 15;
    const int h0  = hh * 32 + (threadIdx.x & 7) * 4;   // 4 h per thread
    const int nt2 = h0 >> 4;
    const int q0  = (h0 >> 2) & 3;
    const int off = (g * 4 + nt2) * 128 + q0 * 32 + l16 * 2;

    float sv0 = 0.f, sv1 = 0.f, sv2 = 0.f, sv3 = 0.f;
    const u32* sp = pnum + (size_t)base * 1024 + off;
    uint2 cur = *(const uint2*)sp;
    for (int ci = 1; ci < cc; ++ci) {
        uint2 nxt = *(const uint2*)(sp + (size_t)ci * 4096);   // next in flight
        sv0 += __uint_as_float(cur.x << 16);
        sv1 += __uint_as_float(cur.x & 0xFFFF0000u);
        sv2 += __uint_as_float(cur.y << 16);
        sv3 += __uint_as_float(cur.y & 0xFFFF0000u);
        cur = nxt;
    }
    sv0 += __uint_as_float(cur.x << 16);
    sv1 += __uint_as_float(cur.x & 0xFFFF0000u);
    sv2 += __uint_as_float(cur.y << 16);
    sv3 += __uint_as_float(cur.y & 0xFFFF0000u);

    const float rd = rden[m];
    float* op = out + (size_t)(bat * T_ + q32 * 32 + m) * 64 + h0;
    f32x4 r;
    r[0] = sv0 * rd; r[1] = sv1 * rd; r[2] = sv2 * rd; r[3] = sv3 * rd;
    *(f32x4*)op = r;
}

// ---------------------------------------------------------------------------
extern "C" void kernel_launch(void* const* d_in, const int* in_sizes, int n_in,
                              void* d_out, int out_size, void* d_ws, size_t ws_size,
                              hipStream_t stream)
{
    const float* x  = (const float*)d_in[0];
    const float* Wk = (const float*)d_in[1];
    const float* Wq = (const float*)d_in[2];
    const float* Wv = (const float*)d_in[3];
    float* out = (float*)d_out;

    u16* ws  = (u16*)d_ws;
    u16* WTf = ws;                          // 98304 u16 (padded to 131072)
    u16* Qf  = ws + 131072;                 // 1048576 u16 each
    u16* Kf  = Qf + 1048576;
    u16* Vf  = Kf + 1048576;
    u32*   pnum = (u32*)(Vf + 1048576);     // partial O (4*1088*1024 u32 reserved)
    float* pden = (float*)(pnum + (size_t)4 * 1088 * 1024);   // fixed offset

    wtrans_kernel<<<48, 256, 0, stream>>>(Wq, Wk, Wv, WTf);
    proj_kernel<<<1024, 256, 0, stream>>>(x, WTf, Qf, Kf, Vf);
    attn_kernel<<<SGRID, 256, 0, stream>>>(Qf, Kf, Vf, pnum, pden, out);
    fin_kernel<<<1024, 256, 0, stream>>>(pnum, pden, out);
}